// Round 7
// baseline (973.522 us; speedup 1.0000x reference)
//
#include <hip/hip_runtime.h>
#include <hip/hip_bf16.h>

// Head: causal single-head attention fwd. B=8,T=2048,C=H=1024, fp32 in.
// Outputs: out[B,T,H] fp32, wei[B,T,T] fp32 (concat in d_out).
//
// Round 12: LDS pipe is the measured bottleneck (64 ds_read_b128 + 32KB DMA
// per block-iter ~= 1024cyc ~= measured 1045). R9's B-direct failed only
// because B was consumed same-iter (raw L2 latency). R12 = B in REGISTERS,
// software-pipelined ONE ITER AHEAD:
//   - A-stream: DMA-staged depth-3 counted-vmcnt (as R11).
//   - B-stream: plain global_load_dwordx4 into named VGPR double-buffer;
//     iter k loads B(k+1) EARLY (before the A-DMA, sched_barrier-fenced so
//     queue order is B-then-DMA), consumes B(k) loaded last iter.
//   - vmcnt: steady queue [A(k), B(k), A(k+1)] -> vmcnt(4) (z0/logits) /
//     vmcnt(2) (z1/out) completes A(k)+B(k), keeps A(k+1) in flight.
//   - LDS: pv/logits 48KB (3 A-slots), out 24KB -> up to 3 blocks/CU.
//   - k-loop unrolled x2 for static B-buffer naming (no dynamic reg index).
// Algebra unchanged: M = Wq^T Wk, P = x M (3-pass f16 hi/lo),
// logits = P x^T (3-pass, causal), v 1-pass, out = wei16 @ vT^T.

#define BB 8
#define TT 2048
#define CC 1024
#define HH 1024
#define BT (BB * TT)

typedef _Float16 f16x8 __attribute__((ext_vector_type(8)));
typedef _Float16 f16x4 __attribute__((ext_vector_type(4)));
typedef float f32x4 __attribute__((ext_vector_type(4)));

#define AS1 __attribute__((address_space(1)))
#define AS3 __attribute__((address_space(3)))

__device__ __forceinline__ void gld16(const _Float16* g, _Float16* lds) {
    __builtin_amdgcn_global_load_lds((AS1 const unsigned int*)g,
                                     (AS3 unsigned int*)lds, 16, 0, 0);
}

// ---------------- Kernel 0a: fp32 -> f16 hi/lo split -------------------------
__global__ __launch_bounds__(256) void split_kernel(
    const float* __restrict__ src, _Float16* __restrict__ dh,
    _Float16* __restrict__ dl, int n)
{
    int i = (blockIdx.x * 256 + threadIdx.x) * 4;
    if (i >= n) return;
    float4 v = *(const float4*)(src + i);
    f16x4 h, l;
    h[0] = (_Float16)v.x; l[0] = (_Float16)(v.x - (float)h[0]);
    h[1] = (_Float16)v.y; l[1] = (_Float16)(v.y - (float)h[1]);
    h[2] = (_Float16)v.z; l[2] = (_Float16)(v.z - (float)h[2]);
    h[3] = (_Float16)v.w; l[3] = (_Float16)(v.w - (float)h[3]);
    *(f16x4*)&dh[i] = h;
    *(f16x4*)&dl[i] = l;
}

// ---------------- Kernel 0b: fp32 W[h,c] -> f16 hi/lo W^T[c,h] ---------------
__global__ __launch_bounds__(256) void splitT_kernel(
    const float* __restrict__ W, _Float16* __restrict__ th,
    _Float16* __restrict__ tl)
{
    __shared__ float L[64][65];
    const int h0 = blockIdx.x * 64;
    const int c0 = blockIdx.y * 64;
    const int tid = threadIdx.x;
    {
        const int hl = tid >> 2;
        const int cs = (tid & 3) * 16;
#pragma unroll
        for (int jj = 0; jj < 16; jj += 4) {
            float4 v = *(const float4*)&W[(size_t)(h0 + hl) * CC + c0 + cs + jj];
            L[cs + jj + 0][hl] = v.x;
            L[cs + jj + 1][hl] = v.y;
            L[cs + jj + 2][hl] = v.z;
            L[cs + jj + 3][hl] = v.w;
        }
    }
    __syncthreads();
    const int c  = tid >> 2;
    const int hs = (tid & 3) * 16;
    f16x8 hv0, hv1, lv0, lv1;
#pragma unroll
    for (int i = 0; i < 8; ++i) {
        float a = L[c][hs + i], b = L[c][hs + 8 + i];
        hv0[i] = (_Float16)a; lv0[i] = (_Float16)(a - (float)hv0[i]);
        hv1[i] = (_Float16)b; lv1[i] = (_Float16)(b - (float)hv1[i]);
    }
    size_t o = (size_t)(c0 + c) * HH + h0 + hs;
    *(f16x8*)&th[o] = hv0; *(f16x8*)&th[o + 8] = hv1;
    *(f16x8*)&tl[o] = lv0; *(f16x8*)&tl[o + 8] = lv1;
}

// ---------------- Kernel 1: M^T = (WqT . WkT^T)^T, 3-pass, tiny --------------
__global__ __launch_bounds__(256, 2) void mm_kernel(
    const _Float16* __restrict__ aH, const _Float16* __restrict__ aL,
    const _Float16* __restrict__ bH, const _Float16* __restrict__ bL,
    _Float16* __restrict__ mtH, _Float16* __restrict__ mtL)
{
    __shared__ _Float16 Ah[4096], Al[4096], Bh[4096], Bl[4096];

    const int n0 = blockIdx.x * 128;
    const int m0 = blockIdx.y * 128;

    const int tid  = threadIdx.x;
    const int r0   = tid & 127;
    const int k0   = tid >> 7;
    const int wave = tid >> 6;
    const int lane = tid & 63;
    const int quad = lane >> 4;
    const int lrow = lane & 15;
    const int wr   = (wave >> 1) * 64;
    const int wc   = (wave & 1) * 64;

    const size_t ga = (size_t)(m0 + r0) * HH + k0 * 8;
    const size_t gb = (size_t)(n0 + r0) * HH + k0 * 8;
    const int lds0 = tid * 8, lds1 = (tid + 256) * 8;

    f32x4 acc[4][4] = {};

    for (int kc = 0; kc < HH; kc += 32) {
        __syncthreads();
        gld16(aH + ga + kc,      &Ah[lds0]);
        gld16(aH + ga + kc + 16, &Ah[lds1]);
        gld16(aL + ga + kc,      &Al[lds0]);
        gld16(aL + ga + kc + 16, &Al[lds1]);
        gld16(bH + gb + kc,      &Bh[lds0]);
        gld16(bH + gb + kc + 16, &Bh[lds1]);
        gld16(bL + gb + kc,      &Bl[lds0]);
        gld16(bL + gb + kc + 16, &Bl[lds1]);
        __syncthreads();

        f16x8 ahf[4], alf[4], bhf[4], blf[4];
#pragma unroll
        for (int i = 0; i < 4; ++i) {
            ahf[i] = *(const f16x8*)&Ah[(quad * 128 + wr + i * 16 + lrow) * 8];
            alf[i] = *(const f16x8*)&Al[(quad * 128 + wr + i * 16 + lrow) * 8];
            bhf[i] = *(const f16x8*)&Bh[(quad * 128 + wc + i * 16 + lrow) * 8];
            blf[i] = *(const f16x8*)&Bl[(quad * 128 + wc + i * 16 + lrow) * 8];
        }
#pragma unroll
        for (int i = 0; i < 4; ++i)
#pragma unroll
            for (int j = 0; j < 4; ++j) {
                acc[i][j] = __builtin_amdgcn_mfma_f32_16x16x32_f16(ahf[i], bhf[j], acc[i][j], 0, 0, 0);
                acc[i][j] = __builtin_amdgcn_mfma_f32_16x16x32_f16(ahf[i], blf[j], acc[i][j], 0, 0, 0);
                acc[i][j] = __builtin_amdgcn_mfma_f32_16x16x32_f16(alf[i], bhf[j], acc[i][j], 0, 0, 0);
            }
    }

    // write transposed: MT[n][m], 4 consecutive m per lane -> f16x4
#pragma unroll
    for (int i = 0; i < 4; ++i)
#pragma unroll
        for (int j = 0; j < 4; ++j) {
            int mm = m0 + wr + i * 16 + quad * 4;
            int nn = n0 + wc + j * 16 + lrow;
            f16x4 ph, pl;
#pragma unroll
            for (int r = 0; r < 4; ++r) {
                float val = acc[i][j][r];
                _Float16 h = (_Float16)val;
                ph[r] = h;
                pl[r] = (_Float16)(val - (float)h);
            }
            *(f16x4*)&mtH[(size_t)nn * CC + mm] = ph;
            *(f16x4*)&mtL[(size_t)nn * CC + mm] = pl;
        }
}

// ---------------- Kernel 2: fused P = x M (3-pass) and v = x Wv^T (1-pass) ---
// A (x) DMA-staged depth-3 counted-vmcnt; B (M^T / Wv) reg-pipelined 1 ahead.
#define EPI_STRIDE 136   // 128 + 8 pad
__global__ __launch_bounds__(256, 2) void pv_kernel(
    const _Float16* __restrict__ xh, const _Float16* __restrict__ xl,
    const _Float16* __restrict__ mtH, const _Float16* __restrict__ mtL,
    const _Float16* __restrict__ Wvh,
    _Float16* __restrict__ Ph, _Float16* __restrict__ Pl,
    _Float16* __restrict__ vT)
{
    // z0: 3 A-slots x (Ah|Al of 4096 f16) = 48KB. z1: 3 x 4096. Epi 17408.
    __shared__ _Float16 S[24576];

    const int idx   = blockIdx.x;
    const int z     = idx >> 10;               // 0: P, 1: v
    const int r     = idx & 1023;
    const int xcd   = r & 7;
    const int j7    = r >> 3;                  // 0..127
    const int mtile = xcd * 16 + (j7 >> 3);    // 0..127
    const int ntile = j7 & 7;                  // 0..7
    const int m0 = mtile * 128;
    const int n0 = ntile * 128;

    const int tid  = threadIdx.x;
    const int r0   = tid & 127;
    const int k0   = tid >> 7;
    const int wave = tid >> 6;
    const int lane = tid & 63;
    const int quad = lane >> 4;
    const int lrow = lane & 15;
    const int wr   = (wave >> 1) * 64;
    const int wc   = (wave & 1) * 64;

    const size_t ga = (size_t)(m0 + r0) * CC + k0 * 8;
    const int lds0 = tid * 8, lds1 = (tid + 256) * 8;

    f32x4 acc[4][4] = {};

    if (z == 0) {
#define PV_A(kc_, sp_) do { \
        _Float16* Sb = S + (sp_) * 8192; \
        gld16(xh + ga + (kc_),      &Sb[lds0]); \
        gld16(xh + ga + (kc_) + 16, &Sb[lds1]); \
        gld16(xl + ga + (kc_),      &Sb[4096 + lds0]); \
        gld16(xl + ga + (kc_) + 16, &Sb[4096 + lds1]); \
    } while (0)

#define PV_ITER0(kc_, BHC, BLC, BHN, BLN) do { \
        asm volatile("s_waitcnt vmcnt(4)" ::: "memory"); \
        __builtin_amdgcn_s_barrier(); \
        __builtin_amdgcn_sched_barrier(0); \
        { int kb = (kc_) + 32; if (kb > CC - 32) kb = CC - 32; \
          _Pragma("unroll") \
          for (int j = 0; j < 4; ++j) { \
              const size_t gbj = (size_t)(n0 + wc + j * 16 + lrow) * CC + kb + quad * 8; \
              BHN[j] = *(const f16x8*)&mtH[gbj]; \
              BLN[j] = *(const f16x8*)&mtL[gbj]; \
          } } \
        __builtin_amdgcn_sched_barrier(0); \
        { int ka = (kc_) + 64; if (ka > CC - 32) ka = CC - 32; \
          int s2 = sa + 2; if (s2 >= 3) s2 -= 3; \
          PV_A(ka, s2); } \
        __builtin_amdgcn_sched_barrier(0); \
        { const _Float16* Ah = S + sa * 8192; \
          const _Float16* Al = Ah + 4096; \
          f16x8 ahf[4], alf[4]; \
          _Pragma("unroll") \
          for (int i = 0; i < 4; ++i) { \
              ahf[i] = *(const f16x8*)&Ah[(quad * 128 + wr + i * 16 + lrow) * 8]; \
              alf[i] = *(const f16x8*)&Al[(quad * 128 + wr + i * 16 + lrow) * 8]; \
          } \
          _Pragma("unroll") \
          for (int i = 0; i < 4; ++i) \
              _Pragma("unroll") \
              for (int j = 0; j < 4; ++j) { \
                  acc[i][j] = __builtin_amdgcn_mfma_f32_16x16x32_f16(ahf[i], BHC[j], acc[i][j], 0, 0, 0); \
                  acc[i][j] = __builtin_amdgcn_mfma_f32_16x16x32_f16(ahf[i], BLC[j], acc[i][j], 0, 0, 0); \
                  acc[i][j] = __builtin_amdgcn_mfma_f32_16x16x32_f16(alf[i], BHC[j], acc[i][j], 0, 0, 0); \
              } } \
        ++sa; if (sa == 3) sa = 0; \
    } while (0)

        // prologue: B(0) regs FIRST (queue order B,A0,A1 -> vmcnt(4) ok)
        f16x8 bhA[4], blA[4], bhB[4], blB[4];
#pragma unroll
        for (int j = 0; j < 4; ++j) {
            const size_t gbj = (size_t)(n0 + wc + j * 16 + lrow) * CC + quad * 8;
            bhA[j] = *(const f16x8*)&mtH[gbj];
            blA[j] = *(const f16x8*)&mtL[gbj];
        }
        __builtin_amdgcn_sched_barrier(0);
        PV_A(0, 0);
        PV_A(32, 1);
        int sa = 0;
        for (int kc = 0; kc < CC; kc += 64) {
            PV_ITER0(kc,      bhA, blA, bhB, blB);
            PV_ITER0(kc + 32, bhB, blB, bhA, blA);
        }
    } else {
#define PV_A1(kc_, sp_) do { \
        _Float16* Sb = S + (sp_) * 4096; \
        gld16(xh + ga + (kc_),      &Sb[lds0]); \
        gld16(xh + ga + (kc_) + 16, &Sb[lds1]); \
    } while (0)

#define PV_ITER1(kc_, BHC, BHN) do { \
        asm volatile("s_waitcnt vmcnt(2)" ::: "memory"); \
        __builtin_amdgcn_s_barrier(); \
        __builtin_amdgcn_sched_barrier(0); \
        { int kb = (kc_) + 32; if (kb > CC - 32) kb = CC - 32; \
          _Pragma("unroll") \
          for (int j = 0; j < 4; ++j) { \
              const size_t gbj = (size_t)(n0 + wc + j * 16 + lrow) * CC + kb + quad * 8; \
              BHN[j] = *(const f16x8*)&Wvh[gbj]; \
          } } \
        __builtin_amdgcn_sched_barrier(0); \
        { int ka = (kc_) + 64; if (ka > CC - 32) ka = CC - 32; \
          int s2 = sl + 2; if (s2 >= 3) s2 -= 3; \
          PV_A1(ka, s2); } \
        __builtin_amdgcn_sched_barrier(0); \
        { const _Float16* Ah = S + sl * 4096; \
          f16x8 ahf[4]; \
          _Pragma("unroll") \
          for (int i = 0; i < 4; ++i) \
              ahf[i] = *(const f16x8*)&Ah[(quad * 128 + wr + i * 16 + lrow) * 8]; \
          _Pragma("unroll") \
          for (int i = 0; i < 4; ++i) \
              _Pragma("unroll") \
              for (int j = 0; j < 4; ++j) \
                  acc[i][j] = __builtin_amdgcn_mfma_f32_16x16x32_f16(ahf[i], BHC[j], acc[i][j], 0, 0, 0); } \
        ++sl; if (sl == 3) sl = 0; \
    } while (0)

        f16x8 bhA[4], bhB[4];
#pragma unroll
        for (int j = 0; j < 4; ++j) {
            const size_t gbj = (size_t)(n0 + wc + j * 16 + lrow) * CC + quad * 8;
            bhA[j] = *(const f16x8*)&Wvh[gbj];
        }
        __builtin_amdgcn_sched_barrier(0);
        PV_A1(0, 0);
        PV_A1(32, 1);
        int sl = 0;
        for (int kc = 0; kc < CC; kc += 64) {
            PV_ITER1(kc,      bhA, bhB);
            PV_ITER1(kc + 32, bhB, bhA);
        }
    }

    // drain in-flight (garbage) prefetches before reusing LDS / kernel end
    asm volatile("s_waitcnt vmcnt(0)" ::: "memory");
    __syncthreads();

    if (z == 1) {
        // stage vT tile [h_local][t_local] in LDS, then coalesced f16x8 stores
#pragma unroll
        for (int i = 0; i < 4; ++i)
#pragma unroll
            for (int j = 0; j < 4; ++j) {
                int hl = wc + j * 16 + lrow;
                int tl = wr + i * 16 + quad * 4;
                f16x4 p;
#pragma unroll
                for (int rr = 0; rr < 4; ++rr) p[rr] = (_Float16)acc[i][j][rr];
                *(f16x4*)&S[hl * EPI_STRIDE + tl] = p;
            }
        __syncthreads();
        const int bi  = mtile >> 4;            // batch of this m-strip
        const int t0g = (mtile & 15) * 128;
        _Float16* vb = vT + (size_t)bi * HH * TT;
#pragma unroll
        for (int rr = 0; rr < 128; rr += 16) {
            int h = rr + (tid >> 4);
            int t = (tid & 15) * 8;
            f16x8 val = *(const f16x8*)&S[h * EPI_STRIDE + t];
            *(f16x8*)&vb[(size_t)(n0 + h) * TT + t0g + t] = val;
        }
    } else {
        // pass 1: hi tile staged [t_local][c_local], coalesced store
#pragma unroll
        for (int i = 0; i < 4; ++i)
#pragma unroll
            for (int j = 0; j < 4; ++j) {
                int tl = wr + i * 16 + quad * 4;
                int cl = wc + j * 16 + lrow;
#pragma unroll
                for (int rr = 0; rr < 4; ++rr)
                    S[(tl + rr) * EPI_STRIDE + cl] = (_Float16)acc[i][j][rr];
            }
        __syncthreads();
#pragma unroll
        for (int rr = 0; rr < 128; rr += 16) {
            int t = rr + (tid >> 4);
            int c = (tid & 15) * 8;
            f16x8 val = *(const f16x8*)&S[t * EPI_STRIDE + c];
            *(f16x8*)&Ph[(size_t)(m0 + t) * CC + n0 + c] = val;
        }
        // pass 2: lo tile
        __syncthreads();
#pragma unroll
        for (int i = 0; i < 4; ++i)
#pragma unroll
            for (int j = 0; j < 4; ++j) {
                int tl = wr + i * 16 + quad * 4;
                int cl = wc + j * 16 + lrow;
#pragma unroll
                for (int rr = 0; rr < 4; ++rr) {
                    float val = acc[i][j][rr];
                    _Float16 h = (_Float16)val;
                    S[(tl + rr) * EPI_STRIDE + cl] = (_Float16)(val - (float)h);
                }
            }
        __syncthreads();
#pragma unroll
        for (int rr = 0; rr < 128; rr += 16) {
            int t = rr + (tid >> 4);
            int c = (tid & 15) * 8;
            f16x8 val = *(const f16x8*)&S[t * EPI_STRIDE + c];
            *(f16x8*)&Pl[(size_t)(m0 + t) * CC + n0 + c] = val;
        }
    }
}

// ---------------- Kernel 3: wei = (P x^T)/32, lower-tri 128-tiles, 3-pass ----
// A (P hi/lo) DMA-staged depth-3; B (x hi/lo) reg-pipelined 1 ahead.
__global__ __launch_bounds__(256, 2) void logits_kernel(
    const _Float16* __restrict__ Ph, const _Float16* __restrict__ Pl,
    const _Float16* __restrict__ xh, const _Float16* __restrict__ xl,
    float* __restrict__ wei)
{
    __shared__ _Float16 S[24576];   // 3 A-slots x (Ph|Pl of 4096 f16) = 48KB

    const int id  = blockIdx.x;
    const int b   = id & 7;          // batch == XCD
    const int tri = id >> 3;         // 0..135, row-major lower triangle
    int tt = (int)((sqrtf(8.0f * (float)tri + 1.0f) - 1.0f) * 0.5f);
    while ((tt + 1) * (tt + 2) / 2 <= tri) ++tt;
    while (tt * (tt + 1) / 2 > tri) --tt;
    const int st = tri - tt * (tt + 1) / 2;

    const size_t base = (size_t)b * TT * CC;
    float* wb = wei + (size_t)b * TT * TT;
    const int m0 = tt * 128;
    const int n0 = st * 128;

    const int tid  = threadIdx.x;
    const int r0   = tid & 127;
    const int k0   = tid >> 7;
    const int wave = tid >> 6;
    const int lane = tid & 63;
    const int quad = lane >> 4;
    const int lrow = lane & 15;
    const int wr   = (wave >> 1) * 64;
    const int wc   = (wave & 1) * 64;

    const size_t ga = base + (size_t)(m0 + r0) * CC + k0 * 8;
    const _Float16* xhb = xh + base;
    const _Float16* xlb = xl + base;
    const int lds0 = tid * 8, lds1 = (tid + 256) * 8;

    f32x4 acc[4][4] = {};

#define LG_A(kc_, sp_) do { \
    _Float16* Sb = S + (sp_) * 8192; \
    gld16(Ph + ga + (kc_),      &Sb[lds0]); \
    gld16(Ph + ga + (kc_) + 16, &Sb[lds1]); \
    gld16(Pl + ga + (kc_),      &Sb[4096 + lds0]); \
    gld16(Pl + ga + (kc_) + 16, &Sb[4096 + lds1]); \
} while (0)

#define LG_ITER(kc_, BHC, BLC, BHN, BLN) do { \
    asm volatile("s_waitcnt vmcnt(4)" ::: "memory"); \
    __builtin_amdgcn_s_barrier(); \
    __builtin_amdgcn_sched_barrier(0); \
    { int kb = (kc_) + 32; if (kb > CC - 32) kb = CC - 32; \
      _Pragma("unroll") \
      for (int j = 0; j < 4; ++j) { \
          const size_t gbj = (size_t)(n0 + wc + j * 16 + lrow) * CC + kb + quad * 8; \
          BHN[j] = *(const f16x8*)&xhb[gbj]; \
          BLN[j] = *(const f16x8*)&xlb[gbj]; \
      } } \
    __builtin_amdgcn_sched_barrier(0); \
    { int ka = (kc_) + 64; if (ka > CC - 32) ka = CC - 32; \
      int s2 = sa + 2; if (s2 >= 3) s2 -= 3; \
      LG_A(ka, s2); } \
    __builtin_amdgcn_sched_barrier(0); \
    { const _Float16* Ah = S + sa * 8192; \
      const _Float16* Al = Ah + 4096; \
      f16x8 ahf[4], alf[4]; \
      _Pragma("unroll") \
      for (int i = 0; i < 4; ++i) { \
          ahf[i] = *(const f16x8*)&Ah[(quad * 128 + wr + i * 16 + lrow) * 8]; \
          alf[i] = *(const f16x8*)&Al[(quad * 128 + wr + i * 16 + lrow) * 8]; \
      } \
      _Pragma("unroll") \
      for (int i = 0; i < 4; ++i) \
          _Pragma("unroll") \
          for (int j = 0; j < 4; ++j) { \
              acc[i][j] = __builtin_amdgcn_mfma_f32_16x16x32_f16(ahf[i], BHC[j], acc[i][j], 0, 0, 0); \
              acc[i][j] = __builtin_amdgcn_mfma_f32_16x16x32_f16(ahf[i], BLC[j], acc[i][j], 0, 0, 0); \
              acc[i][j] = __builtin_amdgcn_mfma_f32_16x16x32_f16(alf[i], BHC[j], acc[i][j], 0, 0, 0); \
          } } \
    ++sa; if (sa == 3) sa = 0; \
} while (0)

    f16x8 bhA[4], blA[4], bhB[4], blB[4];
#pragma unroll
    for (int j = 0; j < 4; ++j) {
        const size_t gbj = (size_t)(n0 + wc + j * 16 + lrow) * CC + quad * 8;
        bhA[j] = *(const f16x8*)&xhb[gbj];
        blA[j] = *(const f16x8*)&xlb[gbj];
    }
    __builtin_amdgcn_sched_barrier(0);
    LG_A(0, 0);
    LG_A(32, 1);
    int sa = 0;
    for (int kc = 0; kc < CC; kc += 64) {
        LG_ITER(kc,      bhA, blA, bhB, blB);
        LG_ITER(kc + 32, bhB, blB, bhA, blA);
    }

    // drain garbage prefetches before kernel end (LDS dealloc hazard)
    asm volatile("s_waitcnt vmcnt(0)" ::: "memory");

    const float scale = 0.03125f;   // 1024^-0.5
#pragma unroll
    for (int i = 0; i < 4; ++i)
#pragma unroll
        for (int j = 0; j < 4; ++j)
#pragma unroll
            for (int r = 0; r < 4; ++r) {
                int rr = wr + i * 16 + quad * 4 + r;
                int cc = wc + j * 16 + lrow;
                wb[(size_t)(m0 + rr) * TT + n0 + cc] = acc[i][j][r] * scale;
            }
}

// ---------------- Kernel 4: causal softmax; writes fp32 wei + f16 wei16 ------
__global__ __launch_bounds__(256) void softmax_kernel(
    float* __restrict__ wei, _Float16* __restrict__ wei16)
{
    const int t = blockIdx.x;
    const int b = blockIdx.y;
    float* row = wei + (size_t)b * TT * TT + (size_t)t * TT;
    _Float16* row16 = wei16 + (size_t)b * TT * TT + (size_t)t * TT;
    const int n = t + 1;
    const int tid = threadIdx.x;
    const int base = tid * 8;

    float vals[8];
    if (base < n) {
        float4 v0 = *(const float4*)&row[base];
        float4 v1 = *(const float4*)&row[base + 4];
        vals[0] = v0.x; vals[1] = v0.y; vals[2] = v0.z; vals[3] = v0.w;
        vals[4] = v1.x; vals[5] = v1.y; vals[6] = v1.z; vals[7] = v1.w;
    } else {
#pragma unroll
        for (int i = 0; i < 8; ++i) vals[i] = -INFINITY;
    }

    float mx = -INFINITY;
#pragma unroll
    for (int i = 0; i < 8; ++i) {
        if (base + i >= n) vals[i] = -INFINITY;
        mx = fmaxf(mx, vals[i]);
    }
#pragma unroll
    for (int off = 32; off > 0; off >>= 1)
        mx = fmaxf(mx, __shfl_down(mx, off));

    __shared__ float redm[4];
    __shared__ float reds[4];
    if ((tid & 63) == 0) redm[tid >> 6] = mx;
    __syncthreads();
    const float m = fmaxf(fmaxf(redm[0], redm[1]), fmaxf(redm[2], redm[3]));

    float sum = 0.f;
#pragma unroll
    for (int i = 0; i < 8; ++i) {
        vals[i] = __expf(vals[i] - m);
        sum += vals[i];
    }
#pragma unroll
    for (int off = 32; off > 0; off >>= 1)
        sum += __shfl_down(sum, off);
    if ((tid & 63) == 0) reds[tid >> 6] = sum;
    __syncthreads();
    const float inv = 1.0f / (reds[0] + reds[1] + reds[2] + reds[3]);

    f16x8 h;
#pragma unroll
    for (int i = 0; i < 8; ++i) {
        float w = vals[i] * inv;     // masked: exp(-inf)*inv = 0 exactly
        vals[i] = w;
        h[i] = (_Float16)w;
    }
    *(float4*)&row[base]     = make_float4(vals[0], vals[1], vals[2], vals[3]);
    *(float4*)&row[base + 4] = make_float4(vals[4], vals[5], vals[6], vals[7]);
    *(f16x8*)&row16[base]    = h;
}

// ---------------- Kernel 5: out = wei16 @ vT^T (NT, f16, causal K) -----------
// A (wei16) DMA-staged depth-3; B (vT rows) reg-pipelined 1 ahead.
__global__ __launch_bounds__(256, 3) void out_kernel(
    const _Float16* __restrict__ wei16, const _Float16* __restrict__ vT,
    float* __restrict__ out)
{
    __shared__ _Float16 S[12288];   // 3 A-slots x 4096 f16 = 24KB

    const int id = blockIdx.x;
    const int b  = id & 7;          // batch == XCD
    const int r  = id >> 3;         // 0..127
    const int tt = 15 - (r >> 3);   // heavy tiles dispatched first
    const int nb = r & 7;

    const _Float16* wb = wei16 + (size_t)b * TT * TT;
    const _Float16* vb = vT    + (size_t)b * HH * TT;
    float*          ob = out   + (size_t)b * TT * HH;

    const int m0 = tt * 128;
    const int n0 = nb * 128;
    const int kend = (tt + 1) * 128;  // wei16==0 above diagonal

    const int tid  = threadIdx.x;
    const int r0   = tid & 127;
    const int k0   = tid >> 7;
    const int wave = tid >> 6;
    const int lane = tid & 63;
    const int quad = lane >> 4;
    const int lrow = lane & 15;
    const int wr   = (wave >> 1) * 64;
    const int wc   = (wave & 1) * 64;

    const size_t ga = (size_t)(m0 + r0) * TT + k0 * 8;
    const int lds0 = tid * 8, lds1 = (tid + 256) * 8;

    f32x4 acc[4][4] = {};

#define OUT_A(kc_, sp_) do { \
    _Float16* Sb = S + (sp_) * 4096; \
    gld16(wb + ga + (kc_),      &Sb[lds0]); \
    gld16(wb + ga + (kc_) + 16, &Sb[lds1]); \
} while (0)

#define OUT_ITER(kc_, BHC, BHN) do { \
    asm volatile("s_waitcnt vmcnt(2)" ::: "memory"); \
    __builtin_amdgcn_s_barrier(); \
    __builtin_amdgcn_sched_barrier(0); \
    { int kb = (kc_) + 32; if (kb > kend - 32) kb = kend - 32; \
      _Pragma("unroll") \
      for (int j = 0; j < 4; ++j) { \
          const size_t gbj = (size_t)(n0 + wc + j * 16 + lrow) * TT + kb + quad * 8; \
          BHN[j] = *(const f16x8*)&vb[gbj]; \
      } } \
    __builtin_amdgcn_sched_barrier(0); \
    { int ka = (kc_) + 64; if (ka > kend - 32) ka = kend - 32; \
      int s2 = sl + 2; if (s2 >= 3) s2 -= 3; \
      OUT_A(ka, s2); } \
    __builtin_amdgcn_sched_barrier(0); \
    { const _Float16* Ah = S + sl * 4096; \
      f16x8 ahf[4]; \
      _Pragma("unroll") \
      for (int i = 0; i < 4; ++i) \
          ahf[i] = *(const f16x8*)&Ah[(quad * 128 + wr + i * 16 + lrow) * 8]; \
      _Pragma("unroll") \
      for (int i = 0; i < 4; ++i) \
          _Pragma("unroll") \
          for (int j = 0; j < 4; ++j) \
              acc[i][j] = __builtin_amdgcn_mfma_f32_16x16x32_f16(ahf[i], BHC[j], acc[i][j], 0, 0, 0); } \
    ++sl; if (sl == 3) sl = 0; \
} while (0)

    f16x8 bvA[4], bvB[4];
#pragma unroll
    for (int j = 0; j < 4; ++j)
        bvA[j] = *(const f16x8*)&vb[(size_t)(n0 + wc + j * 16 + lrow) * TT + quad * 8];
    __builtin_amdgcn_sched_barrier(0);
    OUT_A(0, 0);
    OUT_A(32, 1);
    int sl = 0;
    for (int kc = 0; kc < kend; kc += 64) {
        OUT_ITER(kc,      bvA, bvB);
        OUT_ITER(kc + 32, bvB, bvA);
    }

    // drain garbage prefetches before kernel end (LDS dealloc hazard)
    asm volatile("s_waitcnt vmcnt(0)" ::: "memory");

#pragma unroll
    for (int i = 0; i < 4; ++i)
#pragma unroll
        for (int j = 0; j < 4; ++j)
#pragma unroll
            for (int r2 = 0; r2 < 4; ++r2) {
                int rr = wr + i * 16 + quad * 4 + r2;
                int cc = wc + j * 16 + lrow;
                ob[(size_t)(m0 + rr) * HH + n0 + cc] = acc[i][j][r2];
            }
}

extern "C" void kernel_launch(void* const* d_in, const int* in_sizes, int n_in,
                              void* d_out, int out_size, void* d_ws, size_t ws_size,
                              hipStream_t stream)
{
    const float* x  = (const float*)d_in[0];
    const float* Wk = (const float*)d_in[1];
    const float* Wq = (const float*)d_in[2];
    const float* Wv = (const float*)d_in[3];

    const size_t NX = (size_t)BT * CC;          // 16M
    const size_t NW = (size_t)HH * CC;          // 1M

    float* out = (float*)d_out;                 // [8,2048,1024] fp32
    float* wei = out + (size_t)BT * HH;         // [8,2048,2048] fp32

    // W-derived scratch in d_out's OUT region (64MB; dead before out_kernel)
    _Float16* WqTh = (_Float16*)out;            // [C,H]
    _Float16* WqTl = WqTh + NW;
    _Float16* WkTh = WqTl + NW;
    _Float16* WkTl = WkTh + NW;
    _Float16* Wvh  = WkTl + NW;                 // [H,C]
    _Float16* Wvl  = Wvh  + NW;                 // scratch (unused)
    _Float16* MTh  = Wvl  + NW;                 // [C,C] = M^T
    _Float16* MTl  = MTh  + NW;                 // total 16MB < 64MB

    // ws: 160MB = 5 x 32MB
    _Float16* xh = (_Float16*)d_ws;
    _Float16* xl = xh + NX;
    _Float16* Ph = xl + NX;
    _Float16* Pl = Ph + NX;
    _Float16* vT = Pl + NX;                     // [B][H][T]
    _Float16* wei16 = (_Float16*)d_ws;          // overlays xh/xl/Ph after logits

    split_kernel<<<dim3(NX / 1024), 256, 0, stream>>>(x, xh, xl, (int)NX);
    splitT_kernel<<<dim3(HH / 64, CC / 64), 256, 0, stream>>>(Wq, WqTh, WqTl);
    splitT_kernel<<<dim3(HH / 64, CC / 64), 256, 0, stream>>>(Wk, WkTh, WkTl);
    split_kernel<<<dim3(NW / 1024), 256, 0, stream>>>(Wv, Wvh, Wvl, (int)NW);

    mm_kernel<<<dim3(CC / 128, CC / 128), 256, 0, stream>>>(
        WqTh, WqTl, WkTh, WkTl, MTh, MTl);
    pv_kernel<<<dim3(2048), 256, 0, stream>>>(
        xh, xl, MTh, MTl, Wvh, Ph, Pl, vT);
    logits_kernel<<<dim3(136 * BB), 256, 0, stream>>>(
        Ph, Pl, xh, xl, wei);
    softmax_kernel<<<dim3(TT, BB), 256, 0, stream>>>(wei, wei16);
    out_kernel<<<dim3(128 * BB), 256, 0, stream>>>(wei16, vT, out);
}

// Round 8
// 843.844 us; speedup vs baseline: 1.1537x; 1.1537x over previous
//
#include <hip/hip_runtime.h>
#include <hip/hip_bf16.h>

// Head: causal single-head attention fwd. B=8,T=2048,C=H=1024, fp32 in.
// Outputs: out[B,T,H] fp32, wei[B,T,T] fp32 (concat in d_out).
//
// Round 13: 128^2 tile is LDS-port-bound structurally (R6/R8/R11 all converge
// at ~1045cyc/blk-iter = LDS demand; R9/R12 proved the TCP path is worse).
// Fix the BYTES/FLOP, not the schedule: 256^2 tile, BK=32, 8 waves (2m x 4n,
// wave=128x64), hi/lo 4-stream. LDS reads/FLOP -33%, DMA writes/FLOP -50% ->
// MFMA-bound (3725 vs 2760 cyc/iter). Per-iter compute ~3700cyc >> 900cyc HBM
// latency -> the simple __syncthreads-drain double-buffer suffices (stage
// issued post-barrier completes before next barrier). 128KB LDS, 1 blk/CU.
//   - pv: z0 (P=xM 3-pass) + z1 (v=xWv 1-pass) at 256^2; grid 512, z-interleaved.
//   - logits: off-diagonal 256-tiles (28x8=224 blocks) at 256^2; diagonal
//     256-tiles decompose into 3 x 128-tiles each -> logits_diag (192 blocks,
//     proven R11 asym-depth pipeline, new (tt,st) mapping).
//   - out/softmax/split/mm unchanged (R11).
// Algebra unchanged: M = Wq^T Wk, P = x M (3-pass f16 hi/lo),
// logits = P x^T (3-pass, causal), v 1-pass, out = wei16 @ vT^T.

#define BB 8
#define TT 2048
#define CC 1024
#define HH 1024
#define BT (BB * TT)

typedef _Float16 f16x8 __attribute__((ext_vector_type(8)));
typedef _Float16 f16x4 __attribute__((ext_vector_type(4)));
typedef float f32x4 __attribute__((ext_vector_type(4)));

#define AS1 __attribute__((address_space(1)))
#define AS3 __attribute__((address_space(3)))

__device__ __forceinline__ void gld16(const _Float16* g, _Float16* lds) {
    __builtin_amdgcn_global_load_lds((AS1 const unsigned int*)g,
                                     (AS3 unsigned int*)lds, 16, 0, 0);
}

// ---------------- Kernel 0a: fp32 -> f16 hi/lo split -------------------------
__global__ __launch_bounds__(256) void split_kernel(
    const float* __restrict__ src, _Float16* __restrict__ dh,
    _Float16* __restrict__ dl, int n)
{
    int i = (blockIdx.x * 256 + threadIdx.x) * 4;
    if (i >= n) return;
    float4 v = *(const float4*)(src + i);
    f16x4 h, l;
    h[0] = (_Float16)v.x; l[0] = (_Float16)(v.x - (float)h[0]);
    h[1] = (_Float16)v.y; l[1] = (_Float16)(v.y - (float)h[1]);
    h[2] = (_Float16)v.z; l[2] = (_Float16)(v.z - (float)h[2]);
    h[3] = (_Float16)v.w; l[3] = (_Float16)(v.w - (float)h[3]);
    *(f16x4*)&dh[i] = h;
    *(f16x4*)&dl[i] = l;
}

// ---------------- Kernel 0b: fp32 W[h,c] -> f16 hi/lo W^T[c,h] ---------------
__global__ __launch_bounds__(256) void splitT_kernel(
    const float* __restrict__ W, _Float16* __restrict__ th,
    _Float16* __restrict__ tl)
{
    __shared__ float L[64][65];
    const int h0 = blockIdx.x * 64;
    const int c0 = blockIdx.y * 64;
    const int tid = threadIdx.x;
    {
        const int hl = tid >> 2;
        const int cs = (tid & 3) * 16;
#pragma unroll
        for (int jj = 0; jj < 16; jj += 4) {
            float4 v = *(const float4*)&W[(size_t)(h0 + hl) * CC + c0 + cs + jj];
            L[cs + jj + 0][hl] = v.x;
            L[cs + jj + 1][hl] = v.y;
            L[cs + jj + 2][hl] = v.z;
            L[cs + jj + 3][hl] = v.w;
        }
    }
    __syncthreads();
    const int c  = tid >> 2;
    const int hs = (tid & 3) * 16;
    f16x8 hv0, hv1, lv0, lv1;
#pragma unroll
    for (int i = 0; i < 8; ++i) {
        float a = L[c][hs + i], b = L[c][hs + 8 + i];
        hv0[i] = (_Float16)a; lv0[i] = (_Float16)(a - (float)hv0[i]);
        hv1[i] = (_Float16)b; lv1[i] = (_Float16)(b - (float)hv1[i]);
    }
    size_t o = (size_t)(c0 + c) * HH + h0 + hs;
    *(f16x8*)&th[o] = hv0; *(f16x8*)&th[o + 8] = hv1;
    *(f16x8*)&tl[o] = lv0; *(f16x8*)&tl[o + 8] = lv1;
}

// ---------------- Kernel 1: M^T = (WqT . WkT^T)^T, 3-pass, tiny --------------
__global__ __launch_bounds__(256, 2) void mm_kernel(
    const _Float16* __restrict__ aH, const _Float16* __restrict__ aL,
    const _Float16* __restrict__ bH, const _Float16* __restrict__ bL,
    _Float16* __restrict__ mtH, _Float16* __restrict__ mtL)
{
    __shared__ _Float16 Ah[4096], Al[4096], Bh[4096], Bl[4096];

    const int n0 = blockIdx.x * 128;
    const int m0 = blockIdx.y * 128;

    const int tid  = threadIdx.x;
    const int r0   = tid & 127;
    const int k0   = tid >> 7;
    const int wave = tid >> 6;
    const int lane = tid & 63;
    const int quad = lane >> 4;
    const int lrow = lane & 15;
    const int wr   = (wave >> 1) * 64;
    const int wc   = (wave & 1) * 64;

    const size_t ga = (size_t)(m0 + r0) * HH + k0 * 8;
    const size_t gb = (size_t)(n0 + r0) * HH + k0 * 8;
    const int lds0 = tid * 8, lds1 = (tid + 256) * 8;

    f32x4 acc[4][4] = {};

    for (int kc = 0; kc < HH; kc += 32) {
        __syncthreads();
        gld16(aH + ga + kc,      &Ah[lds0]);
        gld16(aH + ga + kc + 16, &Ah[lds1]);
        gld16(aL + ga + kc,      &Al[lds0]);
        gld16(aL + ga + kc + 16, &Al[lds1]);
        gld16(bH + gb + kc,      &Bh[lds0]);
        gld16(bH + gb + kc + 16, &Bh[lds1]);
        gld16(bL + gb + kc,      &Bl[lds0]);
        gld16(bL + gb + kc + 16, &Bl[lds1]);
        __syncthreads();

        f16x8 ahf[4], alf[4], bhf[4], blf[4];
#pragma unroll
        for (int i = 0; i < 4; ++i) {
            ahf[i] = *(const f16x8*)&Ah[(quad * 128 + wr + i * 16 + lrow) * 8];
            alf[i] = *(const f16x8*)&Al[(quad * 128 + wr + i * 16 + lrow) * 8];
            bhf[i] = *(const f16x8*)&Bh[(quad * 128 + wc + i * 16 + lrow) * 8];
            blf[i] = *(const f16x8*)&Bl[(quad * 128 + wc + i * 16 + lrow) * 8];
        }
#pragma unroll
        for (int i = 0; i < 4; ++i)
#pragma unroll
            for (int j = 0; j < 4; ++j) {
                acc[i][j] = __builtin_amdgcn_mfma_f32_16x16x32_f16(ahf[i], bhf[j], acc[i][j], 0, 0, 0);
                acc[i][j] = __builtin_amdgcn_mfma_f32_16x16x32_f16(ahf[i], blf[j], acc[i][j], 0, 0, 0);
                acc[i][j] = __builtin_amdgcn_mfma_f32_16x16x32_f16(alf[i], bhf[j], acc[i][j], 0, 0, 0);
            }
    }

    // write transposed: MT[n][m], 4 consecutive m per lane -> f16x4
#pragma unroll
    for (int i = 0; i < 4; ++i)
#pragma unroll
        for (int j = 0; j < 4; ++j) {
            int mm = m0 + wr + i * 16 + quad * 4;
            int nn = n0 + wc + j * 16 + lrow;
            f16x4 ph, pl;
#pragma unroll
            for (int r = 0; r < 4; ++r) {
                float val = acc[i][j][r];
                _Float16 h = (_Float16)val;
                ph[r] = h;
                pl[r] = (_Float16)(val - (float)h);
            }
            *(f16x4*)&mtH[(size_t)nn * CC + mm] = ph;
            *(f16x4*)&mtL[(size_t)nn * CC + mm] = pl;
        }
}

// ---------------- Kernel 2: fused P = x M (3-pass) and v = x Wv^T (1-pass) ---
// 256^2 tile, BK=32, 8 waves (2m x 4n; wave = 128x64), double-buffered
// __syncthreads pipeline. z interleaved in blockIdx for CU load balance.
__global__ __launch_bounds__(512, 2) void pv_kernel(
    const _Float16* __restrict__ xh, const _Float16* __restrict__ xl,
    const _Float16* __restrict__ mtH, const _Float16* __restrict__ mtL,
    const _Float16* __restrict__ Wvh,
    _Float16* __restrict__ Ph, _Float16* __restrict__ Pl,
    _Float16* __restrict__ vT)
{
    __shared__ _Float16 S[65536];   // 128KB: z0: 2 x (Ah|Al|Bh|Bl of 8192)

    const int id = blockIdx.x;
    const int z  = id & 1;             // 0: P, 1: v
    const int q  = id >> 1;            // 0..255
    const int xcd = q & 7;
    const int s   = q >> 3;            // 0..31
    const int mtile = xcd * 8 + (s >> 2);   // 0..63
    const int ntile = s & 3;                // 0..3
    const int m0 = mtile * 256;
    const int n0 = ntile * 256;

    const int tid  = threadIdx.x;
    const int wave = tid >> 6;
    const int lane = tid & 63;
    const int quad = lane >> 4;
    const int lrow = lane & 15;
    const int mw   = wave >> 2;        // 0..1 (m-half)
    const int nw   = wave & 3;         // 0..3 (n-quarter)

    const size_t ga = (size_t)(m0 + (tid & 255)) * CC + (tid >> 8) * 8;
    const size_t gb = (size_t)(n0 + (tid & 255)) * CC + (tid >> 8) * 8;
    const int lds0 = tid * 8, lds1 = (tid + 512) * 8;

    f32x4 acc[8][4] = {};

    if (z == 0) {
#define ST0(kc_, buf_) do { \
        _Float16* Sb = S + (buf_) * 32768; \
        gld16(xh  + ga + (kc_),      &Sb[lds0]); \
        gld16(xh  + ga + (kc_) + 16, &Sb[lds1]); \
        gld16(xl  + ga + (kc_),      &Sb[8192 + lds0]); \
        gld16(xl  + ga + (kc_) + 16, &Sb[8192 + lds1]); \
        gld16(mtH + gb + (kc_),      &Sb[16384 + lds0]); \
        gld16(mtH + gb + (kc_) + 16, &Sb[16384 + lds1]); \
        gld16(mtL + gb + (kc_),      &Sb[24576 + lds0]); \
        gld16(mtL + gb + (kc_) + 16, &Sb[24576 + lds1]); \
    } while (0)
        ST0(0, 0);
        int cur = 0;
        for (int kc = 0; kc < CC; kc += 32) {
            __syncthreads();            // drains stage(kc) + prior reads
            if (kc + 32 < CC) ST0(kc + 32, cur ^ 1);

            const _Float16* Ab = S + cur * 32768;
            const _Float16* Al_ = Ab + 8192;
            const _Float16* Bb = Ab + 16384;
            const _Float16* Bl_ = Ab + 24576;

            f16x8 bh[4], bl[4];
#pragma unroll
            for (int j = 0; j < 4; ++j) {
                int c = (quad * 256 + nw * 64 + j * 16 + lrow) * 8;
                bh[j] = *(const f16x8*)&Bb[c];
                bl[j] = *(const f16x8*)&Bl_[c];
            }
#pragma unroll
            for (int i = 0; i < 8; ++i) {
                int a = (quad * 256 + mw * 128 + i * 16 + lrow) * 8;
                f16x8 ah = *(const f16x8*)&Ab[a];
                f16x8 al = *(const f16x8*)&Al_[a];
#pragma unroll
                for (int j = 0; j < 4; ++j) {
                    acc[i][j] = __builtin_amdgcn_mfma_f32_16x16x32_f16(ah, bh[j], acc[i][j], 0, 0, 0);
                    acc[i][j] = __builtin_amdgcn_mfma_f32_16x16x32_f16(ah, bl[j], acc[i][j], 0, 0, 0);
                    acc[i][j] = __builtin_amdgcn_mfma_f32_16x16x32_f16(al, bh[j], acc[i][j], 0, 0, 0);
                }
            }
            cur ^= 1;
        }

        // epilogue: Ph then Pl, per m-half, staged [128][264] coalesced
#pragma unroll
        for (int stream = 0; stream < 2; ++stream) {
            _Float16* dst = stream ? Pl : Ph;
#pragma unroll
            for (int h = 0; h < 2; ++h) {
                __syncthreads();
                if (mw == h) {
#pragma unroll
                    for (int i = 0; i < 8; ++i)
#pragma unroll
                        for (int j = 0; j < 4; ++j)
#pragma unroll
                            for (int rr = 0; rr < 4; ++rr) {
                                float v = acc[i][j][rr];
                                _Float16 hi = (_Float16)v;
                                _Float16 e = stream ? (_Float16)(v - (float)hi) : hi;
                                S[(i * 16 + quad * 4 + rr) * 264 + nw * 64 + j * 16 + lrow] = e;
                            }
                }
                __syncthreads();
#pragma unroll
                for (int w = 0; w < 8; ++w) {
                    int x = w * 512 + tid;
                    int row = x >> 5;
                    int c8 = (x & 31) * 8;
                    *(f16x8*)&dst[(size_t)(m0 + h * 128 + row) * CC + n0 + c8] =
                        *(const f16x8*)&S[row * 264 + c8];
                }
            }
        }
    } else {
#define ST1(kc_, buf_) do { \
        _Float16* Sb = S + (buf_) * 16384; \
        gld16(xh  + ga + (kc_),      &Sb[lds0]); \
        gld16(xh  + ga + (kc_) + 16, &Sb[lds1]); \
        gld16(Wvh + gb + (kc_),      &Sb[8192 + lds0]); \
        gld16(Wvh + gb + (kc_) + 16, &Sb[8192 + lds1]); \
    } while (0)
        ST1(0, 0);
        int cur = 0;
        for (int kc = 0; kc < CC; kc += 32) {
            __syncthreads();
            if (kc + 32 < CC) ST1(kc + 32, cur ^ 1);

            const _Float16* Ab = S + cur * 16384;
            const _Float16* Bb = Ab + 8192;

            f16x8 bh[4];
#pragma unroll
            for (int j = 0; j < 4; ++j)
                bh[j] = *(const f16x8*)&Bb[(quad * 256 + nw * 64 + j * 16 + lrow) * 8];
#pragma unroll
            for (int i = 0; i < 8; ++i) {
                f16x8 ah = *(const f16x8*)&Ab[(quad * 256 + mw * 128 + i * 16 + lrow) * 8];
#pragma unroll
                for (int j = 0; j < 4; ++j)
                    acc[i][j] = __builtin_amdgcn_mfma_f32_16x16x32_f16(ah, bh[j], acc[i][j], 0, 0, 0);
            }
            cur ^= 1;
        }

        // epilogue: vT [h][t] staged [256][136], per t-half, coalesced along t
        const int bi  = mtile >> 3;
        const int t0g = (mtile & 7) * 256;
        _Float16* vb = vT + (size_t)bi * HH * TT;
#pragma unroll
        for (int h = 0; h < 2; ++h) {
            __syncthreads();
            if (mw == h) {
#pragma unroll
                for (int i = 0; i < 8; ++i)
#pragma unroll
                    for (int j = 0; j < 4; ++j) {
                        f16x4 p;
#pragma unroll
                        for (int rr = 0; rr < 4; ++rr) p[rr] = (_Float16)acc[i][j][rr];
                        *(f16x4*)&S[(nw * 64 + j * 16 + lrow) * 136 + i * 16 + quad * 4] = p;
                    }
            }
            __syncthreads();
#pragma unroll
            for (int w = 0; w < 8; ++w) {
                int x = w * 512 + tid;
                int hrow = x >> 4;
                int t8 = (x & 15) * 8;
                *(f16x8*)&vb[(size_t)(n0 + hrow) * TT + t0g + h * 128 + t8] =
                    *(const f16x8*)&S[hrow * 136 + t8];
            }
        }
    }
}

// ---------------- Kernel 3a: logits off-diagonal 256-tiles, 3-pass -----------
// Strictly-lower 256-tiles: 28 per batch x 8 = 224 blocks (1/CU).
__global__ __launch_bounds__(512, 2) void logits_kernel(
    const _Float16* __restrict__ Ph, const _Float16* __restrict__ Pl,
    const _Float16* __restrict__ xh, const _Float16* __restrict__ xl,
    float* __restrict__ wei)
{
    __shared__ _Float16 S[65536];   // 2 x (Ah|Al|Bh|Bl of 8192)

    const int id = blockIdx.x;
    const int b  = id & 7;
    const int q  = id >> 3;          // 0..27
    int tt = 1; while (tt * (tt + 1) / 2 <= q) ++tt;
    const int st = q - tt * (tt - 1) / 2;   // st < tt

    const size_t base = (size_t)b * TT * CC;
    float* wb = wei + (size_t)b * TT * TT;
    const int m0 = tt * 256;
    const int n0 = st * 256;

    const int tid  = threadIdx.x;
    const int wave = tid >> 6;
    const int lane = tid & 63;
    const int quad = lane >> 4;
    const int lrow = lane & 15;
    const int mw   = wave >> 2;
    const int nw   = wave & 3;

    const size_t ga = base + (size_t)(m0 + (tid & 255)) * CC + (tid >> 8) * 8;
    const size_t gb = base + (size_t)(n0 + (tid & 255)) * CC + (tid >> 8) * 8;
    const int lds0 = tid * 8, lds1 = (tid + 512) * 8;

    f32x4 acc[8][4] = {};

#define STL(kc_, buf_) do { \
    _Float16* Sb = S + (buf_) * 32768; \
    gld16(Ph + ga + (kc_),      &Sb[lds0]); \
    gld16(Ph + ga + (kc_) + 16, &Sb[lds1]); \
    gld16(Pl + ga + (kc_),      &Sb[8192 + lds0]); \
    gld16(Pl + ga + (kc_) + 16, &Sb[8192 + lds1]); \
    gld16(xh + gb + (kc_),      &Sb[16384 + lds0]); \
    gld16(xh + gb + (kc_) + 16, &Sb[16384 + lds1]); \
    gld16(xl + gb + (kc_),      &Sb[24576 + lds0]); \
    gld16(xl + gb + (kc_) + 16, &Sb[24576 + lds1]); \
} while (0)

    STL(0, 0);
    int cur = 0;
    for (int kc = 0; kc < CC; kc += 32) {
        __syncthreads();
        if (kc + 32 < CC) STL(kc + 32, cur ^ 1);

        const _Float16* Ab = S + cur * 32768;
        const _Float16* Al_ = Ab + 8192;
        const _Float16* Bb = Ab + 16384;
        const _Float16* Bl_ = Ab + 24576;

        f16x8 bh[4], bl[4];
#pragma unroll
        for (int j = 0; j < 4; ++j) {
            int c = (quad * 256 + nw * 64 + j * 16 + lrow) * 8;
            bh[j] = *(const f16x8*)&Bb[c];
            bl[j] = *(const f16x8*)&Bl_[c];
        }
#pragma unroll
        for (int i = 0; i < 8; ++i) {
            int a = (quad * 256 + mw * 128 + i * 16 + lrow) * 8;
            f16x8 ah = *(const f16x8*)&Ab[a];
            f16x8 al = *(const f16x8*)&Al_[a];
#pragma unroll
            for (int j = 0; j < 4; ++j) {
                acc[i][j] = __builtin_amdgcn_mfma_f32_16x16x32_f16(ah, bh[j], acc[i][j], 0, 0, 0);
                acc[i][j] = __builtin_amdgcn_mfma_f32_16x16x32_f16(ah, bl[j], acc[i][j], 0, 0, 0);
                acc[i][j] = __builtin_amdgcn_mfma_f32_16x16x32_f16(al, bh[j], acc[i][j], 0, 0, 0);
            }
        }
        cur ^= 1;
    }

    const float scale = 0.03125f;   // 1024^-0.5
#pragma unroll
    for (int i = 0; i < 8; ++i)
#pragma unroll
        for (int j = 0; j < 4; ++j)
#pragma unroll
            for (int r = 0; r < 4; ++r) {
                int rr = mw * 128 + i * 16 + quad * 4 + r;
                int cc = nw * 64 + j * 16 + lrow;
                wb[(size_t)(m0 + rr) * TT + n0 + cc] = acc[i][j][r] * scale;
            }
}

// ---------------- Kernel 3b: logits diagonal 128-tiles (R11 pipeline) --------
// Each diagonal 256-tile d = 3 x 128-tiles: (2d,2d),(2d+1,2d),(2d+1,2d+1).
// 24 per batch x 8 = 192 blocks. Asym-depth counted-vmcnt (proven R11 body).
__global__ __launch_bounds__(256, 2) void logits_diag_kernel(
    const _Float16* __restrict__ Ph, const _Float16* __restrict__ Pl,
    const _Float16* __restrict__ xh, const _Float16* __restrict__ xl,
    float* __restrict__ wei)
{
    __shared__ _Float16 S[40960];   // A: 3 x 8192 @0; B: 2 x 8192 @24576

    const int id = blockIdx.x;
    const int b  = id & 7;
    const int qq = id >> 3;          // 0..23
    const int d  = qq / 3;
    const int rm = qq - d * 3;
    const int tt = 2 * d + (rm > 0 ? 1 : 0);
    const int st = 2 * d + (rm == 2 ? 1 : 0);

    const size_t base = (size_t)b * TT * CC;
    float* wb = wei + (size_t)b * TT * TT;
    const int m0 = tt * 128;
    const int n0 = st * 128;

    const int tid  = threadIdx.x;
    const int r0   = tid & 127;
    const int k0   = tid >> 7;
    const int wave = tid >> 6;
    const int lane = tid & 63;
    const int quad = lane >> 4;
    const int lrow = lane & 15;
    const int wr   = (wave >> 1) * 64;
    const int wc   = (wave & 1) * 64;

    const size_t ga = base + (size_t)(m0 + r0) * CC + k0 * 8;
    const size_t gb = base + (size_t)(n0 + r0) * CC + k0 * 8;
    const int lds0 = tid * 8, lds1 = (tid + 256) * 8;

    f32x4 acc[4][4] = {};

#define DG_A(kc_, sp_) do { \
    _Float16* Sb = S + (sp_) * 8192; \
    gld16(Ph + ga + (kc_),      &Sb[lds0]); \
    gld16(Ph + ga + (kc_) + 16, &Sb[lds1]); \
    gld16(Pl + ga + (kc_),      &Sb[4096 + lds0]); \
    gld16(Pl + ga + (kc_) + 16, &Sb[4096 + lds1]); \
} while (0)
#define DG_B(kc_, sp_) do { \
    _Float16* Sb = S + 24576 + (sp_) * 8192; \
    gld16(xh + gb + (kc_),      &Sb[lds0]); \
    gld16(xh + gb + (kc_) + 16, &Sb[lds1]); \
    gld16(xl + gb + (kc_),      &Sb[4096 + lds0]); \
    gld16(xl + gb + (kc_) + 16, &Sb[4096 + lds1]); \
} while (0)

    DG_A(0, 0);
    DG_B(0, 0);
    DG_A(32, 1);

    int sa = 0, sb = 0;
    for (int kc = 0; kc < CC; kc += 32) {
        asm volatile("s_waitcnt vmcnt(4)" ::: "memory");
        __builtin_amdgcn_s_barrier();
        __builtin_amdgcn_sched_barrier(0);

        int kb = kc + 32; if (kb > CC - 32) kb = CC - 32;
        DG_B(kb, sb ^ 1);
        int ka = kc + 64; if (ka > CC - 32) ka = CC - 32;
        int s2 = sa + 2; if (s2 >= 3) s2 -= 3;
        DG_A(ka, s2);

        const _Float16* Ah = S + sa * 8192;
        const _Float16* Al = Ah + 4096;
        const _Float16* Bh = S + 24576 + sb * 8192;
        const _Float16* Bl = Bh + 4096;

        f16x8 ahf[4], alf[4], bhf[4], blf[4];
#pragma unroll
        for (int i = 0; i < 4; ++i) {
            ahf[i] = *(const f16x8*)&Ah[(quad * 128 + wr + i * 16 + lrow) * 8];
            alf[i] = *(const f16x8*)&Al[(quad * 128 + wr + i * 16 + lrow) * 8];
            bhf[i] = *(const f16x8*)&Bh[(quad * 128 + wc + i * 16 + lrow) * 8];
            blf[i] = *(const f16x8*)&Bl[(quad * 128 + wc + i * 16 + lrow) * 8];
        }
#pragma unroll
        for (int i = 0; i < 4; ++i)
#pragma unroll
            for (int j = 0; j < 4; ++j) {
                acc[i][j] = __builtin_amdgcn_mfma_f32_16x16x32_f16(ahf[i], bhf[j], acc[i][j], 0, 0, 0);
                acc[i][j] = __builtin_amdgcn_mfma_f32_16x16x32_f16(ahf[i], blf[j], acc[i][j], 0, 0, 0);
                acc[i][j] = __builtin_amdgcn_mfma_f32_16x16x32_f16(alf[i], bhf[j], acc[i][j], 0, 0, 0);
            }

        ++sa; if (sa == 3) sa = 0;
        sb ^= 1;
    }

    // drain garbage prefetches before kernel end (LDS dealloc hazard)
    asm volatile("s_waitcnt vmcnt(0)" ::: "memory");

    const float scale = 0.03125f;   // 1024^-0.5
#pragma unroll
    for (int i = 0; i < 4; ++i)
#pragma unroll
        for (int j = 0; j < 4; ++j)
#pragma unroll
            for (int r = 0; r < 4; ++r) {
                int rr = wr + i * 16 + quad * 4 + r;
                int cc = wc + j * 16 + lrow;
                wb[(size_t)(m0 + rr) * TT + n0 + cc] = acc[i][j][r] * scale;
            }
}

// ---------------- Kernel 4: causal softmax; writes fp32 wei + f16 wei16 ------
__global__ __launch_bounds__(256) void softmax_kernel(
    float* __restrict__ wei, _Float16* __restrict__ wei16)
{
    const int t = blockIdx.x;
    const int b = blockIdx.y;
    float* row = wei + (size_t)b * TT * TT + (size_t)t * TT;
    _Float16* row16 = wei16 + (size_t)b * TT * TT + (size_t)t * TT;
    const int n = t + 1;
    const int tid = threadIdx.x;
    const int base = tid * 8;

    float vals[8];
    if (base < n) {
        float4 v0 = *(const float4*)&row[base];
        float4 v1 = *(const float4*)&row[base + 4];
        vals[0] = v0.x; vals[1] = v0.y; vals[2] = v0.z; vals[3] = v0.w;
        vals[4] = v1.x; vals[5] = v1.y; vals[6] = v1.z; vals[7] = v1.w;
    } else {
#pragma unroll
        for (int i = 0; i < 8; ++i) vals[i] = -INFINITY;
    }

    float mx = -INFINITY;
#pragma unroll
    for (int i = 0; i < 8; ++i) {
        if (base + i >= n) vals[i] = -INFINITY;
        mx = fmaxf(mx, vals[i]);
    }
#pragma unroll
    for (int off = 32; off > 0; off >>= 1)
        mx = fmaxf(mx, __shfl_down(mx, off));

    __shared__ float redm[4];
    __shared__ float reds[4];
    if ((tid & 63) == 0) redm[tid >> 6] = mx;
    __syncthreads();
    const float m = fmaxf(fmaxf(redm[0], redm[1]), fmaxf(redm[2], redm[3]));

    float sum = 0.f;
#pragma unroll
    for (int i = 0; i < 8; ++i) {
        vals[i] = __expf(vals[i] - m);
        sum += vals[i];
    }
#pragma unroll
    for (int off = 32; off > 0; off >>= 1)
        sum += __shfl_down(sum, off);
    if ((tid & 63) == 0) reds[tid >> 6] = sum;
    __syncthreads();
    const float inv = 1.0f / (reds[0] + reds[1] + reds[2] + reds[3]);

    f16x8 h;
#pragma unroll
    for (int i = 0; i < 8; ++i) {
        float w = vals[i] * inv;     // masked: exp(-inf)*inv = 0 exactly
        vals[i] = w;
        h[i] = (_Float16)w;
    }
    *(float4*)&row[base]     = make_float4(vals[0], vals[1], vals[2], vals[3]);
    *(float4*)&row[base + 4] = make_float4(vals[4], vals[5], vals[6], vals[7]);
    *(f16x8*)&row16[base]    = h;
}

// ---------------- Kernel 5: out = wei16 @ vT^T (NT, f16, causal K) -----------
// R11: compact 1-D grid, batch == XCD, heavy tiles first, depth-3 pipeline.
__global__ __launch_bounds__(256, 3) void out_kernel(
    const _Float16* __restrict__ wei16, const _Float16* __restrict__ vT,
    float* __restrict__ out)
{
    __shared__ _Float16 S[24576];   // 3 slots x (Ah|Bh of 4096 f16) = 48KB

    const int id = blockIdx.x;
    const int b  = id & 7;          // batch == XCD
    const int r  = id >> 3;         // 0..127
    const int tt = 15 - (r >> 3);   // heavy tiles dispatched first
    const int nb = r & 7;

    const _Float16* wb = wei16 + (size_t)b * TT * TT;
    const _Float16* vb = vT    + (size_t)b * HH * TT;
    float*          ob = out   + (size_t)b * TT * HH;

    const int m0 = tt * 128;
    const int n0 = nb * 128;
    const int kend = (tt + 1) * 128;  // wei16==0 above diagonal

    const int tid  = threadIdx.x;
    const int r0   = tid & 127;
    const int k0   = tid >> 7;
    const int wave = tid >> 6;
    const int lane = tid & 63;
    const int quad = lane >> 4;
    const int lrow = lane & 15;
    const int wr   = (wave >> 1) * 64;
    const int wc   = (wave & 1) * 64;

    const size_t ga = (size_t)(m0 + r0) * TT + k0 * 8;
    const size_t gb = (size_t)(n0 + r0) * TT + k0 * 8;
    const int lds0 = tid * 8, lds1 = (tid + 256) * 8;

    f32x4 acc[4][4] = {};

#define OUT_STAGE(kc_, sp_) do { \
    _Float16* Sb = S + (sp_) * 8192; \
    gld16(wb + ga + (kc_),      &Sb[lds0]); \
    gld16(wb + ga + (kc_) + 16, &Sb[lds1]); \
    gld16(vb + gb + (kc_),      &Sb[4096 + lds0]); \
    gld16(vb + gb + (kc_) + 16, &Sb[4096 + lds1]); \
} while (0)

    OUT_STAGE(0, 0);
    OUT_STAGE(32, 1);

    int sl = 0;
    for (int kc = 0; kc < kend; kc += 32) {
        asm volatile("s_waitcnt vmcnt(4)" ::: "memory");
        __builtin_amdgcn_s_barrier();
        __builtin_amdgcn_sched_barrier(0);

        int kpre = kc + 64;
        if (kpre > kend - 32) kpre = kend - 32;
        int s2 = sl + 2; if (s2 >= 3) s2 -= 3;
        OUT_STAGE(kpre, s2);

        const _Float16* Ah = S + sl * 8192;
        const _Float16* Bh = Ah + 4096;

        f16x8 ahf[4], bhf[4];
#pragma unroll
        for (int i = 0; i < 4; ++i) {
            ahf[i] = *(const f16x8*)&Ah[(quad * 128 + wr + i * 16 + lrow) * 8];
            bhf[i] = *(const f16x8*)&Bh[(quad * 128 + wc + i * 16 + lrow) * 8];
        }
#pragma unroll
        for (int i = 0; i < 4; ++i)
#pragma unroll
            for (int j = 0; j < 4; ++j)
                acc[i][j] = __builtin_amdgcn_mfma_f32_16x16x32_f16(ahf[i], bhf[j], acc[i][j], 0, 0, 0);

        ++sl; if (sl == 3) sl = 0;
    }

    // drain garbage prefetches before kernel end (LDS dealloc hazard)
    asm volatile("s_waitcnt vmcnt(0)" ::: "memory");

#pragma unroll
    for (int i = 0; i < 4; ++i)
#pragma unroll
        for (int j = 0; j < 4; ++j)
#pragma unroll
            for (int r2 = 0; r2 < 4; ++r2) {
                int rr = wr + i * 16 + quad * 4 + r2;
                int cc = wc + j * 16 + lrow;
                ob[(size_t)(m0 + rr) * HH + n0 + cc] = acc[i][j][r2];
            }
}

extern "C" void kernel_launch(void* const* d_in, const int* in_sizes, int n_in,
                              void* d_out, int out_size, void* d_ws, size_t ws_size,
                              hipStream_t stream)
{
    const float* x  = (const float*)d_in[0];
    const float* Wk = (const float*)d_in[1];
    const float* Wq = (const float*)d_in[2];
    const float* Wv = (const float*)d_in[3];

    const size_t NX = (size_t)BT * CC;          // 16M
    const size_t NW = (size_t)HH * CC;          // 1M

    float* out = (float*)d_out;                 // [8,2048,1024] fp32
    float* wei = out + (size_t)BT * HH;         // [8,2048,2048] fp32

    // W-derived scratch in d_out's OUT region (64MB; dead before out_kernel)
    _Float16* WqTh = (_Float16*)out;            // [C,H]
    _Float16* WqTl = WqTh + NW;
    _Float16* WkTh = WqTl + NW;
    _Float16* WkTl = WkTh + NW;
    _Float16* Wvh  = WkTl + NW;                 // [H,C]
    _Float16* Wvl  = Wvh  + NW;                 // scratch (unused)
    _Float16* MTh  = Wvl  + NW;                 // [C,C] = M^T
    _Float16* MTl  = MTh  + NW;                 // total 16MB < 64MB

    // ws: 160MB = 5 x 32MB
    _Float16* xh = (_Float16*)d_ws;
    _Float16* xl = xh + NX;
    _Float16* Ph = xl + NX;
    _Float16* Pl = Ph + NX;
    _Float16* vT = Pl + NX;                     // [B][H][T]
    _Float16* wei16 = (_Float16*)d_ws;          // overlays xh/xl/Ph after logits

    split_kernel<<<dim3(NX / 1024), 256, 0, stream>>>(x, xh, xl, (int)NX);
    splitT_kernel<<<dim3(HH / 64, CC / 64), 256, 0, stream>>>(Wq, WqTh, WqTl);
    splitT_kernel<<<dim3(HH / 64, CC / 64), 256, 0, stream>>>(Wk, WkTh, WkTl);
    split_kernel<<<dim3(NW / 1024), 256, 0, stream>>>(Wv, Wvh, Wvl, (int)NW);

    mm_kernel<<<dim3(CC / 128, CC / 128), 256, 0, stream>>>(
        WqTh, WqTl, WkTh, WkTl, MTh, MTl);
    pv_kernel<<<dim3(512), 512, 0, stream>>>(
        xh, xl, MTh, MTl, Wvh, Ph, Pl, vT);
    logits_kernel<<<dim3(28 * BB), 512, 0, stream>>>(
        Ph, Pl, xh, xl, wei);
    logits_diag_kernel<<<dim3(24 * BB), 256, 0, stream>>>(
        Ph, Pl, xh, xl, wei);
    softmax_kernel<<<dim3(TT, BB), 256, 0, stream>>>(wei, wei16);
    out_kernel<<<dim3(128 * BB), 256, 0, stream>>>(wei16, vT, out);
}